// Round 14
// baseline (734.170 us; speedup 1.0000x reference)
//
#include <hip/hip_runtime.h>
#include <math.h>

#define BB 2
#define NN 512
#define SDIM 384
#define ZDIM 128
#define HH 12
#define CDIM 16
#define PQ 4
#define PV 8
#define BN (BB*NN)        // 1024
#define CATD 2112

#define WL  0.57735026918962576f
#define LAM 0.06804138174397717f   // wL*wC/2, wC = sqrt(2/(9*PQ))

// ---- workspace layout (float offsets) ----
#define OFF_Q    0                         // [1024][192] rows
#define OFF_QP   196608                    // [1024][144] rows
#define OFF_QQ   344064                    // [1024][12]
#define OFF_KT4  356352                    // f4: [2][48][512]  (c4-group major, n minor)
#define OFF_KPT4 552960                    // f4: [2][36][512]
#define OFF_KKT  700416                    // [2][12][512]
#define OFF_V    712704                    // [1024][192] rows (f4 view [1024][48])
#define OFF_VP   909312                    // [1024][288] rows (f4 view [1024][72])
#define OFF_CAT  7495680                   // [1024][2112]

__device__ __forceinline__ float dot4(float4 a, float4 b) {
    return a.x*b.x + a.y*b.y + a.z*b.z + a.w*b.w;
}
__device__ __forceinline__ void fma4(float4& a, float s, float4 b) {
    a.x += s*b.x; a.y += s*b.y; a.z += s*b.z; a.w += s*b.w;
}
__device__ __forceinline__ void add4(float4& a, float4 b) {
    a.x += b.x; a.y += b.y; a.z += b.z; a.w += b.w;
}
__device__ __forceinline__ void mul4(float4& a, float s) {
    a.x *= s; a.y *= s; a.z *= s; a.w *= s;
}

// ---------------- Kernel 1: projections + frame transform -------------------
// 2 rows per block, 512 blocks. s rows read via scalar loads (uniform).
__global__ __launch_bounds__(256) void k_proj(
    const float* __restrict__ s, const float* __restrict__ Rg, const float* __restrict__ tg,
    const float* __restrict__ Wq, const float* __restrict__ Wk, const float* __restrict__ Wv,
    const float* __restrict__ Wqp, const float* __restrict__ Wkp, const float* __restrict__ Wvp,
    float* __restrict__ ws)
{
    __shared__ float4 pL4[2][144];   // point projections (local frame), rows 0/1
    __shared__ float  sqL[2][96];    // |qp|^2 [0:48), |kp|^2 [48:96)
    __shared__ float  Rt[2][12];
    const int t = threadIdx.x;
    const int n0 = blockIdx.x * 2;
    const int b  = n0 >> 9;
    const int nloc = n0 & 511;

    if (t < 24) {
        int rr = t / 12, c = t % 12;
        Rt[rr][c] = (c < 9) ? Rg[(n0+rr)*9 + c] : tg[(n0+rr)*3 + (c-9)];
    }
    const float* s0 = s + (size_t)n0*SDIM;
    const float* s1 = s0 + SDIM;
    __syncthreads();

    float4* Q4g  = (float4*)(ws + OFF_Q);
    float4* V4g  = (float4*)(ws + OFF_V);
    float4* KT4g = (float4*)(ws + OFF_KT4);

    for (int it = 0; it < 2; ++it) {
        int g = t + it*256;
        if (g >= 288) break;
        const float4* W4; int wc4, ld4, dst;
        if (g < 48)       { W4 = (const float4*)Wq;  wc4 = g;     ld4 = 48; dst = 0; }
        else if (g < 96)  { W4 = (const float4*)Wk;  wc4 = g-48;  ld4 = 48; dst = 1; }
        else if (g < 144) { W4 = (const float4*)Wv;  wc4 = g-96;  ld4 = 48; dst = 2; }
        else if (g < 180) { W4 = (const float4*)Wqp; wc4 = g-144; ld4 = 36; dst = 3; }
        else if (g < 216) { W4 = (const float4*)Wkp; wc4 = g-180; ld4 = 36; dst = 4; }
        else              { W4 = (const float4*)Wvp; wc4 = g-216; ld4 = 72; dst = 5; }
        float4 acc0 = {0,0,0,0}, acc1 = {0,0,0,0};
        #pragma unroll 4
        for (int r = 0; r < SDIM; ++r) {
            float4 wv = W4[r*ld4 + wc4];
            float f0 = s0[r], f1 = s1[r];
            fma4(acc0, f0, wv);
            fma4(acc1, f1, wv);
        }
        if (dst == 0) {
            Q4g[(size_t)n0*48 + wc4] = acc0;
            Q4g[(size_t)(n0+1)*48 + wc4] = acc1;
        } else if (dst == 1) {
            size_t base = ((size_t)(b*48 + wc4))*512 + nloc;
            KT4g[base] = acc0; KT4g[base+1] = acc1;
        } else if (dst == 2) {
            V4g[(size_t)n0*48 + wc4] = acc0;
            V4g[(size_t)(n0+1)*48 + wc4] = acc1;
        } else if (dst == 3) {
            pL4[0][wc4] = acc0; pL4[1][wc4] = acc1;
        } else if (dst == 4) {
            pL4[0][36+wc4] = acc0; pL4[1][36+wc4] = acc1;
        } else {
            pL4[0][72+wc4] = acc0; pL4[1][72+wc4] = acc1;
        }
    }
    __syncthreads();

    // local -> global frame
    for (int task = t; task < 384; task += 256) {
        int rr = task / 192, pt = task % 192;
        const float* pl = (const float*)pL4[rr];
        int off = (pt < 48) ? pt*3 : (pt < 96 ? 144 + (pt-48)*3 : 288 + (pt-96)*3);
        float p0 = pl[off], p1 = pl[off+1], p2 = pl[off+2];
        const float* R = Rt[rr];
        float g0 = R[0]*p0 + R[1]*p1 + R[2]*p2 + R[9];
        float g1 = R[3]*p0 + R[4]*p1 + R[5]*p2 + R[10];
        float g2 = R[6]*p0 + R[7]*p1 + R[8]*p2 + R[11];
        int bn = n0 + rr, n = bn & 511;
        if (pt < 48) {
            int o = pt*3;
            float* d = ws + OFF_QP + (size_t)bn*144 + o;
            d[0] = g0; d[1] = g1; d[2] = g2;
            sqL[rr][pt] = g0*g0 + g1*g1 + g2*g2;
        } else if (pt < 96) {
            int pc = (pt-48)*3;
            float gg[3] = {g0,g1,g2};
            #pragma unroll
            for (int x = 0; x < 3; ++x) {
                int pcx = pc + x;
                ws[OFF_KPT4 + (((size_t)(b*36 + (pcx>>2)))*512 + n)*4 + (pcx&3)] = gg[x];
            }
            sqL[rr][pt] = g0*g0 + g1*g1 + g2*g2;
        } else {
            int o = (pt-96)*3;
            float* d = ws + OFF_VP + (size_t)bn*288 + o;
            d[0] = g0; d[1] = g1; d[2] = g2;
        }
    }
    __syncthreads();

    if (t < 48) {
        int rr = t / 24, u = t % 24;
        int bn = n0 + rr, n = bn & 511;
        if (u < 12) {
            float sm = sqL[rr][u*4] + sqL[rr][u*4+1] + sqL[rr][u*4+2] + sqL[rr][u*4+3];
            ws[OFF_QQ + (size_t)bn*12 + u] = sm;
        } else {
            int h = u - 12;
            float sm = sqL[rr][48+h*4] + sqL[rr][48+h*4+1] + sqL[rr][48+h*4+2] + sqL[rr][48+h*4+3];
            ws[OFF_KKT + ((size_t)(b*12 + h))*512 + n] = sm;
        }
    }
}

// ---------------- Kernel 2: fused attention per (b,i) -----------------------
// Phase A/B: round-7 proven. Phase C v3 (r13): typ0 = 128 thr x 12 heads,
// typ1/2 = 320 thr x 8 segments. NEW: launch_bounds(512,3) -> VGPR cap ~85
// -> 3 blocks/CU (LDS 41.5KB allows 3); typ0 indexes aL directly (no
// pointer array) to fit the tighter register budget.
__global__ __launch_bounds__(512, 3) void k_attn(
    const float* __restrict__ z, const float* __restrict__ Rg, const float* __restrict__ tg,
    const float* __restrict__ hw, const float* __restrict__ Wb, float* __restrict__ ws)
{
    // probs: 12 rows stride 516 (6192 f); scratch overlay: 2496 f4 (9984 f)
    __shared__ __align__(16) float aL[9984];
    __shared__ float4 optgS4[72];
    __shared__ float RiL[9], tiL[3], sInv[12];

    const int t = threadIdx.x;
    // batch-aware XCD swizzle: XCDs 0..3 get batch 0, 4..7 batch 1 (perf only)
    const int d = blockIdx.x;
    const int xcd = d & 7, slot = d >> 3;
    const int bi = (xcd < 4) ? (xcd*128 + slot) : (512 + (xcd-4)*128 + slot);
    const int b = bi >> 9;

    if (t < 9)             RiL[t]   = Rg[bi*9 + t];
    if (t >= 9 && t < 12)  tiL[t-9] = tg[bi*3 + (t-9)];

    // ---- phase A: inline pair bias + logits, thread <-> j (r7 proven) ----
    {
        const int j = t;
        float pb[HH];
        #pragma unroll
        for (int h = 0; h < HH; ++h) pb[h] = 0.f;
        const float4* zrow4 = (const float4*)z + ((size_t)bi*512 + j)*32;
        #pragma unroll 4
        for (int c4 = 0; c4 < 32; ++c4) {
            const float4 zq = zrow4[c4];
            const float* wb = Wb + c4*48;          // uniform across threads
            #pragma unroll
            for (int e = 0; e < 4; ++e) {
                const float zv = ((const float*)&zq)[e];
                const float* w = wb + e*12;
                #pragma unroll
                for (int h = 0; h < HH; ++h) pb[h] += zv * w[h];
            }
        }
        const float4* Q4u  = (const float4*)(ws + OFF_Q  + (size_t)bi*192);
        const float4* QP4u = (const float4*)(ws + OFF_QP + (size_t)bi*144);
        const float*  QQu  = ws + OFF_QQ + (size_t)bi*12;
        const float4* KT4  = (const float4*)(ws + OFF_KT4)  + (size_t)b*48*512;
        const float4* KPT4 = (const float4*)(ws + OFF_KPT4) + (size_t)b*36*512;
        const float*  KKT  = ws + OFF_KKT  + (size_t)b*12*512;
        for (int h = 0; h < HH; ++h) {
            const float x = hw[h];
            const float gam = (x > 20.f) ? x : log1pf(__expf(x));
            float scal = 0.f, qk = 0.f;
            #pragma unroll
            for (int cg = 0; cg < 4; ++cg)
                scal += dot4(Q4u[h*4+cg], KT4[(h*4+cg)*512 + j]);
            #pragma unroll
            for (int pg = 0; pg < 3; ++pg)
                qk += dot4(QP4u[h*3+pg], KPT4[(h*3+pg)*512 + j]);
            float dist2 = QQu[h] + KKT[h*512 + j] - 2.f*qk;
            aL[h*516 + j] = WL*(scal*0.25f + pb[h]) - LAM*gam*dist2;
        }
    }
    __syncthreads();

    // ---- phase B: softmax per head (unnormalized e; inv folded into epilogue) ----
    {
        const int w = t >> 6, lane = t & 63;
        for (int h = w; h < HH; h += 8) {
            float* row = aL + h*516;
            float m = -1e30f;
            #pragma unroll
            for (int k = 0; k < 8; ++k) m = fmaxf(m, row[lane + 64*k]);
            #pragma unroll
            for (int off = 32; off > 0; off >>= 1) m = fmaxf(m, __shfl_xor(m, off));
            float ssum = 0.f;
            #pragma unroll
            for (int k = 0; k < 8; ++k) {
                float e = __expf(row[lane + 64*k] - m);
                row[lane + 64*k] = e;
                ssum += e;
            }
            #pragma unroll
            for (int off = 32; off > 0; off >>= 1) ssum += __shfl_xor(ssum, off);
            if (lane == 0) sInv[h] = 1.f / ssum;
        }
    }
    __syncthreads();

    // ---- phase C v3 ----
    float4 accT[HH];                 // typ0: all 12 heads
    #pragma unroll
    for (int h = 0; h < HH; ++h) accT[h] = make_float4(0.f, 0.f, 0.f, 0.f);
    float4 acc0={0,0,0,0}, acc1={0,0,0,0}, acc2={0,0,0,0};   // typ1/2

    if (t < 128) {
        // typ0: 4 jseg (waves 0-1) x 32 zc4; 12 heads/thread; 1x z redundancy
        const int seg0 = t >> 5;            // 0..3
        const int zc4 = t & 31;
        const int j0 = seg0*128;            // 128 j per segment, 32 groups of 4
        const float4* Zp = (const float4*)z + (size_t)bi*512*32 + zc4;

// direct aL indexing: one base VGPR + compile-time ds offsets (h*516*4 B)
#define FMA4_12(ZB, JT) do { \
    _Pragma("unroll") \
    for (int h = 0; h < HH; ++h) { \
        const float4 av = *(const float4*)(aL + h*516 + (JT)); \
        fma4(accT[h], av.x, ZB[0]); \
        fma4(accT[h], av.y, ZB[1]); \
        fma4(accT[h], av.z, ZB[2]); \
        fma4(accT[h], av.w, ZB[3]); \
    } \
} while (0)

        float4 zA[4], zB[4];
        #pragma unroll
        for (int e = 0; e < 4; ++e) zA[e] = Zp[(size_t)(j0+e)*32];
        for (int p = 0; p < 32; p += 2) {        // two 4-j groups per iter
            const int jt = j0 + p*4;
            #pragma unroll
            for (int e = 0; e < 4; ++e) zB[e] = Zp[(size_t)(jt+4+e)*32];
            FMA4_12(zA, jt);
            if (p + 2 < 32) {
                #pragma unroll
                for (int e = 0; e < 4; ++e) zA[e] = Zp[(size_t)(jt+8+e)*32];
            }
            FMA4_12(zB, jt + 4);
        }
#undef FMA4_12
    } else if (t < 448) {
        // typ1/typ2: 320 threads = 8 jsegs (64 j each) x 40 slots (V/VP, L2)
        const int v = t - 128;
        const int seg8 = v / 40;
        const int w = v % 40;
        const int j0 = seg8*64, j1 = j0 + 64;
        const float4* P; int S, D, O, hg;
        if (w < 16) {
            hg = w >> 2; S = 48; D = 16; O = hg*4 + (w & 3);
            P = (const float4*)(ws + OFF_V) + (size_t)b*512*48;
        } else {
            const int v2 = w - 16;
            hg = v2 / 6; S = 72; D = 24; O = hg*6 + v2 % 6;
            P = (const float4*)(ws + OFF_VP) + (size_t)b*512*72;
        }
        const float* a0p = aL + hg*516;
        const float* a1p = aL + (hg+4)*516;
        const float* a2p = aL + (hg+8)*516;
        #pragma unroll 2
        for (int jt = j0; jt < j1; jt += 4) {
            float4 av0 = *(const float4*)(a0p + jt);
            float4 av1 = *(const float4*)(a1p + jt);
            float4 av2 = *(const float4*)(a2p + jt);
            #pragma unroll
            for (int e = 0; e < 4; ++e) {
                const size_t base = (size_t)(jt+e)*S + O;
                fma4(acc0, ((const float*)&av0)[e], P[base]);
                fma4(acc1, ((const float*)&av1)[e], P[base + D]);
                fma4(acc2, ((const float*)&av2)[e], P[base + 2*D]);
            }
        }
    }
    __syncthreads();                       // all reads of aL done
    float4* sc4 = (float4*)aL;             // overlay: [0,1536) typ0, [1536,2496) typ1/2
    if (t < 128) {
        const int si = t*12;
        #pragma unroll
        for (int h = 0; h < HH; ++h) sc4[si + h] = accT[h];
    } else if (t < 448) {
        const int si = 1536 + (t-128)*3;
        sc4[si] = acc0; sc4[si+1] = acc1; sc4[si+2] = acc2;
    }
    __syncthreads();

    if (t < 168) {
        float4 r0 = {0,0,0,0}, r1 = {0,0,0,0}, r2 = {0,0,0,0};
        float4* cat4 = (float4*)(ws + OFF_CAT);
        const size_t cb = (size_t)bi * 528;          // 2112/4
        if (t < 128) {
            const int hg = t >> 5, zc4 = t & 31;
            #pragma unroll
            for (int ss = 0; ss < 4; ++ss) {
                const int si = (ss*32 + zc4)*12;
                add4(r0, sc4[si + hg]);
                add4(r1, sc4[si + hg + 4]);
                add4(r2, sc4[si + hg + 8]);
            }
            mul4(r0, sInv[hg]); mul4(r1, sInv[hg+4]); mul4(r2, sInv[hg+8]);
            cat4[cb + 144 + (hg  )*32 + zc4] = r0;
            cat4[cb + 144 + (hg+4)*32 + zc4] = r1;
            cat4[cb + 144 + (hg+8)*32 + zc4] = r2;
        } else {
            const int w = t - 128;
            #pragma unroll
            for (int ss = 0; ss < 8; ++ss) {
                const int si = 1536 + (ss*40 + w)*3;
                add4(r0, sc4[si]); add4(r1, sc4[si+1]); add4(r2, sc4[si+2]);
            }
            if (w < 16) {
                const int hg = w >> 2, c4 = w & 3;
                mul4(r0, sInv[hg]); mul4(r1, sInv[hg+4]); mul4(r2, sInv[hg+8]);
                cat4[cb + (hg  )*4 + c4] = r0;
                cat4[cb + (hg+4)*4 + c4] = r1;
                cat4[cb + (hg+8)*4 + c4] = r2;
            } else {
                const int v2 = w - 16;
                const int hg = v2 / 6, po = v2 % 6;
                mul4(r0, sInv[hg]); mul4(r1, sInv[hg+4]); mul4(r2, sInv[hg+8]);
                optgS4[(hg  )*6 + po] = r0;
                optgS4[(hg+4)*6 + po] = r1;
                optgS4[(hg+8)*6 + po] = r2;
            }
        }
    }
    __syncthreads();

    if (t < 96) {
        const float* og = (const float*)optgS4;
        int h = t >> 3, p = t & 7;
        int o = h*24 + p*3;
        float d0 = og[o]   - tiL[0];
        float d1 = og[o+1] - tiL[1];
        float d2 = og[o+2] - tiL[2];
        float ox = RiL[0]*d0 + RiL[3]*d1 + RiL[6]*d2;
        float oy = RiL[1]*d0 + RiL[4]*d1 + RiL[7]*d2;
        float oz = RiL[2]*d0 + RiL[5]*d1 + RiL[8]*d2;
        float* cat = ws + OFF_CAT + (size_t)bi*CATD;
        cat[192 + o]     = ox;
        cat[192 + o + 1] = oy;
        cat[192 + o + 2] = oz;
        cat[480 + h*8 + p] = sqrtf(ox*ox + oy*oy + oz*oz + 1e-8f);
    }
}

// ---------------- Kernel 3: out = cat @ Wout (LDS-staged cat) ---------------
__global__ __launch_bounds__(384) void k_out(
    const float* __restrict__ Wout, const float* __restrict__ ws, float* __restrict__ out)
{
    __shared__ __align__(16) float catS[4*CATD];   // 33792 B
    const int t = threadIdx.x;                 // col 0..383
    const int row0 = blockIdx.x * 4;
    {
        const float4* src = (const float4*)(ws + OFF_CAT + (size_t)row0*CATD);
        float4* dst = (float4*)catS;
        #pragma unroll
        for (int i = t; i < 4*528; i += 384) dst[i] = src[i];
    }
    __syncthreads();
    const float* c0 = catS;
    const float* c1 = catS + CATD;
    const float* c2 = catS + 2*CATD;
    const float* c3 = catS + 3*CATD;
    float a0 = 0.f, a1 = 0.f, a2 = 0.f, a3 = 0.f;
    #pragma unroll 8
    for (int r = 0; r < CATD; ++r) {
        float w = Wout[(size_t)r*384 + t];
        a0 += c0[r]*w; a1 += c1[r]*w; a2 += c2[r]*w; a3 += c3[r]*w;
    }
    out[(size_t)(row0+0)*384 + t] = a0;
    out[(size_t)(row0+1)*384 + t] = a1;
    out[(size_t)(row0+2)*384 + t] = a2;
    out[(size_t)(row0+3)*384 + t] = a3;
}

extern "C" void kernel_launch(void* const* d_in, const int* in_sizes, int n_in,
                              void* d_out, int out_size, void* d_ws, size_t ws_size,
                              hipStream_t stream)
{
    const float* s    = (const float*)d_in[0];
    const float* z    = (const float*)d_in[1];
    const float* R    = (const float*)d_in[2];
    const float* tt   = (const float*)d_in[3];
    const float* Wq   = (const float*)d_in[4];
    const float* Wk   = (const float*)d_in[5];
    const float* Wv   = (const float*)d_in[6];
    const float* Wqp  = (const float*)d_in[7];
    const float* Wkp  = (const float*)d_in[8];
    const float* Wvp  = (const float*)d_in[9];
    const float* Wb   = (const float*)d_in[10];
    const float* hw   = (const float*)d_in[11];
    const float* Wout = (const float*)d_in[12];
    float* ws  = (float*)d_ws;
    float* out = (float*)d_out;

    hipLaunchKernelGGL(k_proj, dim3(BN/2), dim3(256), 0, stream,
                       s, R, tt, Wq, Wk, Wv, Wqp, Wkp, Wvp, ws);
    hipLaunchKernelGGL(k_attn, dim3(BN),   dim3(512), 0, stream, z, R, tt, hw, Wb, ws);
    hipLaunchKernelGGL(k_out,  dim3(BN/4), dim3(384), 0, stream, Wout, ws, out);
}

// Round 15
// 725.036 us; speedup vs baseline: 1.0126x; 1.0126x over previous
//
#include <hip/hip_runtime.h>
#include <math.h>

#define BB 2
#define NN 512
#define SDIM 384
#define ZDIM 128
#define HH 12
#define CDIM 16
#define PQ 4
#define PV 8
#define BN (BB*NN)        // 1024
#define CATD 2112

#define WL  0.57735026918962576f
#define LAM 0.06804138174397717f   // wL*wC/2, wC = sqrt(2/(9*PQ))

// ---- workspace layout (float offsets) ----
#define OFF_Q    0                         // [1024][192] rows
#define OFF_QP   196608                    // [1024][144] rows
#define OFF_QQ   344064                    // [1024][12]
#define OFF_KT4  356352                    // f4: [2][48][512]  (c4-group major, n minor)
#define OFF_KPT4 552960                    // f4: [2][36][512]
#define OFF_KKT  700416                    // [2][12][512]
#define OFF_V    712704                    // [1024][192] rows (f4 view [1024][48])
#define OFF_VP   909312                    // [1024][288] rows (f4 view [1024][72])
#define OFF_CAT  7495680                   // [1024][2112]

__device__ __forceinline__ float dot4(float4 a, float4 b) {
    return a.x*b.x + a.y*b.y + a.z*b.z + a.w*b.w;
}
__device__ __forceinline__ void fma4(float4& a, float s, float4 b) {
    a.x += s*b.x; a.y += s*b.y; a.z += s*b.z; a.w += s*b.w;
}
__device__ __forceinline__ void add4(float4& a, float4 b) {
    a.x += b.x; a.y += b.y; a.z += b.z; a.w += b.w;
}
__device__ __forceinline__ void mul4(float4& a, float s) {
    a.x *= s; a.y *= s; a.z *= s; a.w *= s;
}

// ---------------- Kernel 1: projections + frame transform -------------------
// 2 rows per block, 512 blocks. s rows read via scalar loads (uniform).
__global__ __launch_bounds__(256) void k_proj(
    const float* __restrict__ s, const float* __restrict__ Rg, const float* __restrict__ tg,
    const float* __restrict__ Wq, const float* __restrict__ Wk, const float* __restrict__ Wv,
    const float* __restrict__ Wqp, const float* __restrict__ Wkp, const float* __restrict__ Wvp,
    float* __restrict__ ws)
{
    __shared__ float4 pL4[2][144];   // point projections (local frame), rows 0/1
    __shared__ float  sqL[2][96];    // |qp|^2 [0:48), |kp|^2 [48:96)
    __shared__ float  Rt[2][12];
    const int t = threadIdx.x;
    const int n0 = blockIdx.x * 2;
    const int b  = n0 >> 9;
    const int nloc = n0 & 511;

    if (t < 24) {
        int rr = t / 12, c = t % 12;
        Rt[rr][c] = (c < 9) ? Rg[(n0+rr)*9 + c] : tg[(n0+rr)*3 + (c-9)];
    }
    const float* s0 = s + (size_t)n0*SDIM;
    const float* s1 = s0 + SDIM;
    __syncthreads();

    float4* Q4g  = (float4*)(ws + OFF_Q);
    float4* V4g  = (float4*)(ws + OFF_V);
    float4* KT4g = (float4*)(ws + OFF_KT4);

    for (int it = 0; it < 2; ++it) {
        int g = t + it*256;
        if (g >= 288) break;
        const float4* W4; int wc4, ld4, dst;
        if (g < 48)       { W4 = (const float4*)Wq;  wc4 = g;     ld4 = 48; dst = 0; }
        else if (g < 96)  { W4 = (const float4*)Wk;  wc4 = g-48;  ld4 = 48; dst = 1; }
        else if (g < 144) { W4 = (const float4*)Wv;  wc4 = g-96;  ld4 = 48; dst = 2; }
        else if (g < 180) { W4 = (const float4*)Wqp; wc4 = g-144; ld4 = 36; dst = 3; }
        else if (g < 216) { W4 = (const float4*)Wkp; wc4 = g-180; ld4 = 36; dst = 4; }
        else              { W4 = (const float4*)Wvp; wc4 = g-216; ld4 = 72; dst = 5; }
        float4 acc0 = {0,0,0,0}, acc1 = {0,0,0,0};
        #pragma unroll 4
        for (int r = 0; r < SDIM; ++r) {
            float4 wv = W4[r*ld4 + wc4];
            float f0 = s0[r], f1 = s1[r];
            fma4(acc0, f0, wv);
            fma4(acc1, f1, wv);
        }
        if (dst == 0) {
            Q4g[(size_t)n0*48 + wc4] = acc0;
            Q4g[(size_t)(n0+1)*48 + wc4] = acc1;
        } else if (dst == 1) {
            size_t base = ((size_t)(b*48 + wc4))*512 + nloc;
            KT4g[base] = acc0; KT4g[base+1] = acc1;
        } else if (dst == 2) {
            V4g[(size_t)n0*48 + wc4] = acc0;
            V4g[(size_t)(n0+1)*48 + wc4] = acc1;
        } else if (dst == 3) {
            pL4[0][wc4] = acc0; pL4[1][wc4] = acc1;
        } else if (dst == 4) {
            pL4[0][36+wc4] = acc0; pL4[1][36+wc4] = acc1;
        } else {
            pL4[0][72+wc4] = acc0; pL4[1][72+wc4] = acc1;
        }
    }
    __syncthreads();

    // local -> global frame
    for (int task = t; task < 384; task += 256) {
        int rr = task / 192, pt = task % 192;
        const float* pl = (const float*)pL4[rr];
        int off = (pt < 48) ? pt*3 : (pt < 96 ? 144 + (pt-48)*3 : 288 + (pt-96)*3);
        float p0 = pl[off], p1 = pl[off+1], p2 = pl[off+2];
        const float* R = Rt[rr];
        float g0 = R[0]*p0 + R[1]*p1 + R[2]*p2 + R[9];
        float g1 = R[3]*p0 + R[4]*p1 + R[5]*p2 + R[10];
        float g2 = R[6]*p0 + R[7]*p1 + R[8]*p2 + R[11];
        int bn = n0 + rr, n = bn & 511;
        if (pt < 48) {
            int o = pt*3;
            float* d = ws + OFF_QP + (size_t)bn*144 + o;
            d[0] = g0; d[1] = g1; d[2] = g2;
            sqL[rr][pt] = g0*g0 + g1*g1 + g2*g2;
        } else if (pt < 96) {
            int pc = (pt-48)*3;
            float gg[3] = {g0,g1,g2};
            #pragma unroll
            for (int x = 0; x < 3; ++x) {
                int pcx = pc + x;
                ws[OFF_KPT4 + (((size_t)(b*36 + (pcx>>2)))*512 + n)*4 + (pcx&3)] = gg[x];
            }
            sqL[rr][pt] = g0*g0 + g1*g1 + g2*g2;
        } else {
            int o = (pt-96)*3;
            float* d = ws + OFF_VP + (size_t)bn*288 + o;
            d[0] = g0; d[1] = g1; d[2] = g2;
        }
    }
    __syncthreads();

    if (t < 48) {
        int rr = t / 24, u = t % 24;
        int bn = n0 + rr, n = bn & 511;
        if (u < 12) {
            float sm = sqL[rr][u*4] + sqL[rr][u*4+1] + sqL[rr][u*4+2] + sqL[rr][u*4+3];
            ws[OFF_QQ + (size_t)bn*12 + u] = sm;
        } else {
            int h = u - 12;
            float sm = sqL[rr][48+h*4] + sqL[rr][48+h*4+1] + sqL[rr][48+h*4+2] + sqL[rr][48+h*4+3];
            ws[OFF_KKT + ((size_t)(b*12 + h))*512 + n] = sm;
        }
    }
}

// ---------------- Kernel 2: fused attention per (b,i) -----------------------
// Phase A/B: round-7 proven (bias unroll 4, compiler-scheduled; barrier-free
// z path — staging/pipelining variants r8/r9/r11 all measured slower).
// Phase C v2 (r10 proven, best measured): typ0 = 192 threads x 6 heads
// (z redundancy halved); typ1/2 = 320 threads over 8 uniform 64-j segments.
// launch_bounds(512,2): (512,3) measured slower (spills, r14).
__global__ __launch_bounds__(512, 2) void k_attn(
    const float* __restrict__ z, const float* __restrict__ Rg, const float* __restrict__ tg,
    const float* __restrict__ hw, const float* __restrict__ Wb, float* __restrict__ ws)
{
    // probs: 12 rows stride 516 (6192 f); scratch: 2112 f4 (8448 f) overlay
    __shared__ __align__(16) float aL[8448];
    __shared__ float4 optgS4[72];
    __shared__ float RiL[9], tiL[3], sInv[12];

    const int t = threadIdx.x;
    // batch-aware XCD swizzle: XCDs 0..3 get batch 0, 4..7 batch 1 (perf only)
    const int d = blockIdx.x;
    const int xcd = d & 7, slot = d >> 3;
    const int bi = (xcd < 4) ? (xcd*128 + slot) : (512 + (xcd-4)*128 + slot);
    const int b = bi >> 9;

    if (t < 9)             RiL[t]   = Rg[bi*9 + t];
    if (t >= 9 && t < 12)  tiL[t-9] = tg[bi*3 + (t-9)];

    // gamma (uniform, per-thread registers)
    float gam[HH];
    #pragma unroll
    for (int h = 0; h < HH; ++h) {
        float x = hw[h];
        gam[h] = (x > 20.f) ? x : log1pf(__expf(x));
    }

    // ---- phase A: inline pair bias + logits, thread <-> j (r7 proven) ----
    {
        const int j = t;
        float pb[HH];
        #pragma unroll
        for (int h = 0; h < HH; ++h) pb[h] = 0.f;
        const float4* zrow4 = (const float4*)z + ((size_t)bi*512 + j)*32;
        #pragma unroll 4
        for (int c4 = 0; c4 < 32; ++c4) {
            const float4 zq = zrow4[c4];
            const float* wb = Wb + c4*48;          // uniform across threads
            #pragma unroll
            for (int e = 0; e < 4; ++e) {
                const float zv = ((const float*)&zq)[e];
                const float* w = wb + e*12;
                #pragma unroll
                for (int h = 0; h < HH; ++h) pb[h] += zv * w[h];
            }
        }
        const float4* Q4u  = (const float4*)(ws + OFF_Q  + (size_t)bi*192);
        const float4* QP4u = (const float4*)(ws + OFF_QP + (size_t)bi*144);
        const float*  QQu  = ws + OFF_QQ + (size_t)bi*12;
        const float4* KT4  = (const float4*)(ws + OFF_KT4)  + (size_t)b*48*512;
        const float4* KPT4 = (const float4*)(ws + OFF_KPT4) + (size_t)b*36*512;
        const float*  KKT  = ws + OFF_KKT  + (size_t)b*12*512;
        for (int h = 0; h < HH; ++h) {
            float scal = 0.f, qk = 0.f;
            #pragma unroll
            for (int cg = 0; cg < 4; ++cg)
                scal += dot4(Q4u[h*4+cg], KT4[(h*4+cg)*512 + j]);
            #pragma unroll
            for (int pg = 0; pg < 3; ++pg)
                qk += dot4(QP4u[h*3+pg], KPT4[(h*3+pg)*512 + j]);
            float dist2 = QQu[h] + KKT[h*512 + j] - 2.f*qk;
            aL[h*516 + j] = WL*(scal*0.25f + pb[h]) - LAM*gam[h]*dist2;
        }
    }
    __syncthreads();

    // ---- phase B: softmax per head (unnormalized e; inv folded into epilogue) ----
    {
        const int w = t >> 6, lane = t & 63;
        for (int h = w; h < HH; h += 8) {
            float* row = aL + h*516;
            float m = -1e30f;
            #pragma unroll
            for (int k = 0; k < 8; ++k) m = fmaxf(m, row[lane + 64*k]);
            #pragma unroll
            for (int off = 32; off > 0; off >>= 1) m = fmaxf(m, __shfl_xor(m, off));
            float ssum = 0.f;
            #pragma unroll
            for (int k = 0; k < 8; ++k) {
                float e = __expf(row[lane + 64*k] - m);
                row[lane + 64*k] = e;
                ssum += e;
            }
            #pragma unroll
            for (int off = 32; off > 0; off >>= 1) ssum += __shfl_xor(ssum, off);
            if (lane == 0) sInv[h] = 1.f / ssum;
        }
    }
    __syncthreads();

    // ---- phase C v2 ----
    float4 acc0={0,0,0,0}, acc1={0,0,0,0}, acc2={0,0,0,0};
    float4 acc3={0,0,0,0}, acc4={0,0,0,0}, acc5={0,0,0,0};

    if (t < 192) {
        // typ0: 3 jseg (waves 0-2) x 2 q x 32 zc4; 6 heads/thread:
        //   accA(0..2) = heads {q, q+4, q+8}; accB(3..5) = heads {q+2, q+6, q+10}
        const int seg0 = t / 64;
        const int r = t & 63;
        const int q = r >> 5, zc4 = r & 31;
        const int j0 = seg0*176;
        const int ngrp = (seg0 == 2) ? 20 : 22;     // groups of 8 j's (even count)
        const float4* Zp = (const float4*)z + (size_t)bi*512*32 + zc4;
        const float* aA0 = aL + (q   )*516;
        const float* aA1 = aL + (q+4 )*516;
        const float* aA2 = aL + (q+8 )*516;
        const float* aB0 = aL + (q+2 )*516;
        const float* aB1 = aL + (q+6 )*516;
        const float* aB2 = aL + (q+10)*516;

#define FMA8_6(ZB, JT) do { \
    float4 vA0 = *(const float4*)(aA0 + (JT)); float4 wA0 = *(const float4*)(aA0 + (JT) + 4); \
    float4 vA1 = *(const float4*)(aA1 + (JT)); float4 wA1 = *(const float4*)(aA1 + (JT) + 4); \
    float4 vA2 = *(const float4*)(aA2 + (JT)); float4 wA2 = *(const float4*)(aA2 + (JT) + 4); \
    float4 vB0 = *(const float4*)(aB0 + (JT)); float4 wB0 = *(const float4*)(aB0 + (JT) + 4); \
    float4 vB1 = *(const float4*)(aB1 + (JT)); float4 wB1 = *(const float4*)(aB1 + (JT) + 4); \
    float4 vB2 = *(const float4*)(aB2 + (JT)); float4 wB2 = *(const float4*)(aB2 + (JT) + 4); \
    fma4(acc0, vA0.x, ZB[0]); fma4(acc1, vA1.x, ZB[0]); fma4(acc2, vA2.x, ZB[0]); \
    fma4(acc3, vB0.x, ZB[0]); fma4(acc4, vB1.x, ZB[0]); fma4(acc5, vB2.x, ZB[0]); \
    fma4(acc0, vA0.y, ZB[1]); fma4(acc1, vA1.y, ZB[1]); fma4(acc2, vA2.y, ZB[1]); \
    fma4(acc3, vB0.y, ZB[1]); fma4(acc4, vB1.y, ZB[1]); fma4(acc5, vB2.y, ZB[1]); \
    fma4(acc0, vA0.z, ZB[2]); fma4(acc1, vA1.z, ZB[2]); fma4(acc2, vA2.z, ZB[2]); \
    fma4(acc3, vB0.z, ZB[2]); fma4(acc4, vB1.z, ZB[2]); fma4(acc5, vB2.z, ZB[2]); \
    fma4(acc0, vA0.w, ZB[3]); fma4(acc1, vA1.w, ZB[3]); fma4(acc2, vA2.w, ZB[3]); \
    fma4(acc3, vB0.w, ZB[3]); fma4(acc4, vB1.w, ZB[3]); fma4(acc5, vB2.w, ZB[3]); \
    fma4(acc0, wA0.x, ZB[4]); fma4(acc1, wA1.x, ZB[4]); fma4(acc2, wA2.x, ZB[4]); \
    fma4(acc3, wB0.x, ZB[4]); fma4(acc4, wB1.x, ZB[4]); fma4(acc5, wB2.x, ZB[4]); \
    fma4(acc0, wA0.y, ZB[5]); fma4(acc1, wA1.y, ZB[5]); fma4(acc2, wA2.y, ZB[5]); \
    fma4(acc3, wB0.y, ZB[5]); fma4(acc4, wB1.y, ZB[5]); fma4(acc5, wB2.y, ZB[5]); \
    fma4(acc0, wA0.z, ZB[6]); fma4(acc1, wA1.z, ZB[6]); fma4(acc2, wA2.z, ZB[6]); \
    fma4(acc3, wB0.z, ZB[6]); fma4(acc4, wB1.z, ZB[6]); fma4(acc5, wB2.z, ZB[6]); \
    fma4(acc0, wA0.w, ZB[7]); fma4(acc1, wA1.w, ZB[7]); fma4(acc2, wA2.w, ZB[7]); \
    fma4(acc3, wB0.w, ZB[7]); fma4(acc4, wB1.w, ZB[7]); fma4(acc5, wB2.w, ZB[7]); \
} while (0)

        float4 zA[8], zB[8];
        #pragma unroll
        for (int e = 0; e < 8; ++e) zA[e] = Zp[(size_t)(j0+e)*32];
        for (int p = 0; p < ngrp; p += 2) {
            const int jt = j0 + p*8;
            #pragma unroll
            for (int e = 0; e < 8; ++e) zB[e] = Zp[(size_t)(jt+8+e)*32];
            FMA8_6(zA, jt);
            if (p + 2 < ngrp) {
                #pragma unroll
                for (int e = 0; e < 8; ++e) zA[e] = Zp[(size_t)(jt+16+e)*32];
            }
            FMA8_6(zB, jt + 8);
        }
#undef FMA8_6
    } else {
        // typ1/typ2: 320 threads = 8 jsegs (64 j each) x 40 slots (V/VP, L2)
        const int v = t - 192;
        const int seg8 = v / 40;
        const int w = v % 40;
        const int j0 = seg8*64, j1 = j0 + 64;
        const float4* P; int S, D, O, hg;
        if (w < 16) {
            hg = w >> 2; S = 48; D = 16; O = hg*4 + (w & 3);
            P = (const float4*)(ws + OFF_V) + (size_t)b*512*48;
        } else {
            const int v2 = w - 16;
            hg = v2 / 6; S = 72; D = 24; O = hg*6 + v2 % 6;
            P = (const float4*)(ws + OFF_VP) + (size_t)b*512*72;
        }
        const float* a0p = aL + hg*516;
        const float* a1p = aL + (hg+4)*516;
        const float* a2p = aL + (hg+8)*516;
        #pragma unroll 2
        for (int jt = j0; jt < j1; jt += 4) {
            float4 av0 = *(const float4*)(a0p + jt);
            float4 av1 = *(const float4*)(a1p + jt);
            float4 av2 = *(const float4*)(a2p + jt);
            #pragma unroll
            for (int e = 0; e < 4; ++e) {
                const size_t base = (size_t)(jt+e)*S + O;
                fma4(acc0, ((const float*)&av0)[e], P[base]);
                fma4(acc1, ((const float*)&av1)[e], P[base + D]);
                fma4(acc2, ((const float*)&av2)[e], P[base + 2*D]);
            }
        }
    }
    __syncthreads();                       // all reads of aL done
    float4* sc4 = (float4*)aL;             // scratch overlay: [0,1152) typ0, [1152,2112) typ1/2
    if (t < 192) {
        const int si = t*6;
        sc4[si]   = acc0; sc4[si+1] = acc1; sc4[si+2] = acc2;
        sc4[si+3] = acc3; sc4[si+4] = acc4; sc4[si+5] = acc5;
    } else {
        const int si = 1152 + (t-192)*3;
        sc4[si] = acc0; sc4[si+1] = acc1; sc4[si+2] = acc2;
    }
    __syncthreads();

    if (t < 168) {
        float4 r0 = {0,0,0,0}, r1 = {0,0,0,0}, r2 = {0,0,0,0};
        float4* cat4 = (float4*)(ws + OFF_CAT);
        const size_t cb = (size_t)bi * 528;          // 2112/4
        if (t < 128) {
            const int hg = t >> 5, zc4 = t & 31;
            const int q = hg & 1, half = hg >> 1;
            #pragma unroll
            for (int ss = 0; ss < 3; ++ss) {
                const int si = (ss*64 + q*32 + zc4)*6 + half*3;
                add4(r0, sc4[si]); add4(r1, sc4[si+1]); add4(r2, sc4[si+2]);
            }
            mul4(r0, sInv[hg]); mul4(r1, sInv[hg+4]); mul4(r2, sInv[hg+8]);
            cat4[cb + 144 + (hg  )*32 + zc4] = r0;
            cat4[cb + 144 + (hg+4)*32 + zc4] = r1;
            cat4[cb + 144 + (hg+8)*32 + zc4] = r2;
        } else {
            const int w = t - 128;
            #pragma unroll
            for (int ss = 0; ss < 8; ++ss) {
                const int si = 1152 + (ss*40 + w)*3;
                add4(r0, sc4[si]); add4(r1, sc4[si+1]); add4(r2, sc4[si+2]);
            }
            if (w < 16) {
                const int hg = w >> 2, c4 = w & 3;
                mul4(r0, sInv[hg]); mul4(r1, sInv[hg+4]); mul4(r2, sInv[hg+8]);
                cat4[cb + (hg  )*4 + c4] = r0;
                cat4[cb + (hg+4)*4 + c4] = r1;
                cat4[cb + (hg+8)*4 + c4] = r2;
            } else {
                const int v2 = w - 16;
                const int hg = v2 / 6, po = v2 % 6;
                mul4(r0, sInv[hg]); mul4(r1, sInv[hg+4]); mul4(r2, sInv[hg+8]);
                optgS4[(hg  )*6 + po] = r0;
                optgS4[(hg+4)*6 + po] = r1;
                optgS4[(hg+8)*6 + po] = r2;
            }
        }
    }
    __syncthreads();

    if (t < 96) {
        const float* og = (const float*)optgS4;
        int h = t >> 3, p = t & 7;
        int o = h*24 + p*3;
        float d0 = og[o]   - tiL[0];
        float d1 = og[o+1] - tiL[1];
        float d2 = og[o+2] - tiL[2];
        float ox = RiL[0]*d0 + RiL[3]*d1 + RiL[6]*d2;
        float oy = RiL[1]*d0 + RiL[4]*d1 + RiL[7]*d2;
        float oz = RiL[2]*d0 + RiL[5]*d1 + RiL[8]*d2;
        float* cat = ws + OFF_CAT + (size_t)bi*CATD;
        cat[192 + o]     = ox;
        cat[192 + o + 1] = oy;
        cat[192 + o + 2] = oz;
        cat[480 + h*8 + p] = sqrtf(ox*ox + oy*oy + oz*oz + 1e-8f);
    }
}

// ---------------- Kernel 3: out = cat @ Wout (LDS-staged cat) ---------------
__global__ __launch_bounds__(384) void k_out(
    const float* __restrict__ Wout, const float* __restrict__ ws, float* __restrict__ out)
{
    __shared__ __align__(16) float catS[4*CATD];   // 33792 B
    const int t = threadIdx.x;                 // col 0..383
    const int row0 = blockIdx.x * 4;
    {
        const float4* src = (const float4*)(ws + OFF_CAT + (size_t)row0*CATD);
        float4* dst = (float4*)catS;
        #pragma unroll
        for (int i = t; i < 4*528; i += 384) dst[i] = src[i];
    }
    __syncthreads();
    const float* c0 = catS;
    const float* c1 = catS + CATD;
    const float* c2 = catS + 2*CATD;
    const float* c3 = catS + 3*CATD;
    float a0 = 0.f, a1 = 0.f, a2 = 0.f, a3 = 0.f;
    #pragma unroll 8
    for (int r = 0; r < CATD; ++r) {
        float w = Wout[(size_t)r*384 + t];
        a0 += c0[r]*w; a1 += c1[r]*w; a2 += c2[r]*w; a3 += c3[r]*w;
    }
    out[(size_t)(row0+0)*384 + t] = a0;
    out[(size_t)(row0+1)*384 + t] = a1;
    out[(size_t)(row0+2)*384 + t] = a2;
    out[(size_t)(row0+3)*384 + t] = a3;
}

extern "C" void kernel_launch(void* const* d_in, const int* in_sizes, int n_in,
                              void* d_out, int out_size, void* d_ws, size_t ws_size,
                              hipStream_t stream)
{
    const float* s    = (const float*)d_in[0];
    const float* z    = (const float*)d_in[1];
    const float* R    = (const float*)d_in[2];
    const float* tt   = (const float*)d_in[3];
    const float* Wq   = (const float*)d_in[4];
    const float* Wk   = (const float*)d_in[5];
    const float* Wv   = (const float*)d_in[6];
    const float* Wqp  = (const float*)d_in[7];
    const float* Wkp  = (const float*)d_in[8];
    const float* Wvp  = (const float*)d_in[9];
    const float* Wb   = (const float*)d_in[10];
    const float* hw   = (const float*)d_in[11];
    const float* Wout = (const float*)d_in[12];
    float* ws  = (float*)d_ws;
    float* out = (float*)d_out;

    hipLaunchKernelGGL(k_proj, dim3(BN/2), dim3(256), 0, stream,
                       s, R, tt, Wq, Wk, Wv, Wqp, Wkp, Wvp, ws);
    hipLaunchKernelGGL(k_attn, dim3(BN),   dim3(512), 0, stream, z, R, tt, hw, Wb, ws);
    hipLaunchKernelGGL(k_out,  dim3(BN/4), dim3(384), 0, stream, Wout, ws, out);
}